// Round 5
// baseline (473.818 us; speedup 1.0000x reference)
//
#include <hip/hip_runtime.h>

#define IN_DIM 256
#define OUT_DIM 64

typedef __attribute__((ext_vector_type(8))) short short8;   // 8 bf16 (4 VGPR)
typedef __attribute__((ext_vector_type(4))) float frag_cd;  // 4 fp32 acc

__device__ __forceinline__ unsigned short bf16_rne(float f) {
    unsigned u = __float_as_uint(f);
    u = (u + 0x7FFFu + ((u >> 16) & 1u)) >> 16;
    return (unsigned short)u;
}
__device__ __forceinline__ float bf16_to_f32(unsigned short h) {
    return __uint_as_float((unsigned)h << 16);
}

// ===== wprep: pack W into per-lane MFMA B-fragments (bf16) + wf0/wf1 = W @ f_w =====
__global__ __launch_bounds__(256) void wprep_kernel(const float* __restrict__ W,
                                                    const float* __restrict__ f_w,
                                                    short8* __restrict__ wfrag,
                                                    float* __restrict__ wf0,
                                                    float* __restrict__ wf1) {
    const int t = threadIdx.x;
    float s0 = 0.f, s1 = 0.f;
    #pragma unroll 8
    for (int c = 0; c < 64; c++) {
        const float w = W[t * 64 + c];
        s0 += w * f_w[c];
        s1 += w * f_w[64 + c];
    }
    wf0[t] = s0;
    wf1[t] = s1;
    for (int e = t; e < 2048; e += 256) {
        const int lane = e & 63;
        const int ct = e >> 6;
        const int chunk = ct >> 2, tile = ct & 3;
        const int kb = chunk * 32 + ((lane >> 4) * 8);
        const int n = tile * 16 + (lane & 15);
        short8 f;
        #pragma unroll
        for (int j = 0; j < 8; j++)
            f[j] = (short)bf16_rne(W[(kb + j) * 64 + n]);
        wfrag[e] = f;
    }
}

// ===== GEMM: pre16 = bf16(x @ W) via MFMA; abl.x/.y = exact fp32 x@wf0, x@wf1 =====
__global__ __launch_bounds__(256) void gemm_kernel(const float* __restrict__ x,
                                                   const short8* __restrict__ wfrag,
                                                   const float* __restrict__ wf0,
                                                   const float* __restrict__ wf1,
                                                   unsigned short* __restrict__ pre16,
                                                   float4* __restrict__ abl, int N) {
    const int t = threadIdx.x;
    const int w = t >> 6;
    const int l = t & 63;
    const int m = l & 15;
    const int q = l >> 4;
    const int row0 = blockIdx.x * 64 + w * 16;
    const int arow = row0 + m;
    const int arowc = (arow < N) ? arow : (N - 1);
    const float* xr = x + (size_t)arowc * IN_DIM;

    frag_cd acc0 = {0.f, 0.f, 0.f, 0.f};
    frag_cd acc1 = acc0, acc2 = acc0, acc3 = acc0;
    float ap = 0.f, bp = 0.f;

    #pragma unroll 2
    for (int c = 0; c < 8; c++) {
        const int k0 = c * 32 + q * 8;
        const float4 xl = *(const float4*)&xr[k0];
        const float4 xh = *(const float4*)&xr[k0 + 4];
        const float4 w0l = *(const float4*)&wf0[k0];
        const float4 w0h = *(const float4*)&wf0[k0 + 4];
        const float4 w1l = *(const float4*)&wf1[k0];
        const float4 w1h = *(const float4*)&wf1[k0 + 4];
        const short8 b0 = wfrag[(c * 4 + 0) * 64 + l];
        const short8 b1 = wfrag[(c * 4 + 1) * 64 + l];
        const short8 b2 = wfrag[(c * 4 + 2) * 64 + l];
        const short8 b3 = wfrag[(c * 4 + 3) * 64 + l];

        ap += xl.x * w0l.x + xl.y * w0l.y + xl.z * w0l.z + xl.w * w0l.w
            + xh.x * w0h.x + xh.y * w0h.y + xh.z * w0h.z + xh.w * w0h.w;
        bp += xl.x * w1l.x + xl.y * w1l.y + xl.z * w1l.z + xl.w * w1l.w
            + xh.x * w1h.x + xh.y * w1h.y + xh.z * w1h.z + xh.w * w1h.w;

        short8 a8;
        a8[0] = (short)bf16_rne(xl.x); a8[1] = (short)bf16_rne(xl.y);
        a8[2] = (short)bf16_rne(xl.z); a8[3] = (short)bf16_rne(xl.w);
        a8[4] = (short)bf16_rne(xh.x); a8[5] = (short)bf16_rne(xh.y);
        a8[6] = (short)bf16_rne(xh.z); a8[7] = (short)bf16_rne(xh.w);

        acc0 = __builtin_amdgcn_mfma_f32_16x16x32_bf16(a8, b0, acc0, 0, 0, 0);
        acc1 = __builtin_amdgcn_mfma_f32_16x16x32_bf16(a8, b1, acc1, 0, 0, 0);
        acc2 = __builtin_amdgcn_mfma_f32_16x16x32_bf16(a8, b2, acc2, 0, 0, 0);
        acc3 = __builtin_amdgcn_mfma_f32_16x16x32_bf16(a8, b3, acc3, 0, 0, 0);
    }

    ap += __shfl_xor(ap, 16, 64); ap += __shfl_xor(ap, 32, 64);
    bp += __shfl_xor(bp, 16, 64); bp += __shfl_xor(bp, 32, 64);
    if (q == 0 && arow < N)
        *(float2*)&abl[arow] = make_float2(ap, bp);   // .x,.y only (.z owned by scan3)

    const frag_cd* accs[4] = {&acc0, &acc1, &acc2, &acc3};
    #pragma unroll
    for (int tt = 0; tt < 4; tt++) {
        #pragma unroll
        for (int r = 0; r < 4; r++) {
            const int ro = row0 + q * 4 + r;
            if (ro < N)
                pre16[(size_t)ro * OUT_DIM + tt * 16 + m] = bf16_rne((*accs[tt])[r]);
        }
    }
}

// ================= degree histogram =================
__global__ __launch_bounds__(256) void degree_kernel(const int* __restrict__ row,
                                                     unsigned* __restrict__ cnt, int E) {
    const int i = blockIdx.x * blockDim.x + threadIdx.x;
    if (i < E) atomicAdd(&cnt[row[i]], 1u);
}

// ================= scan (3-phase) =================
__global__ __launch_bounds__(256) void scan1_kernel(const unsigned* __restrict__ cnt,
                                                    unsigned* __restrict__ incl,
                                                    unsigned* __restrict__ bsum, int N) {
    __shared__ unsigned s[256];
    const int t = threadIdx.x;
    const int i = blockIdx.x * 256 + t;
    const unsigned v = (i < N) ? cnt[i] : 0u;
    s[t] = v; __syncthreads();
    for (int off = 1; off < 256; off <<= 1) {
        const unsigned u = (t >= off) ? s[t - off] : 0u;
        __syncthreads();
        s[t] += u;
        __syncthreads();
    }
    if (i < N) incl[i] = s[t];
    if (t == 255) bsum[blockIdx.x] = s[255];
}

__global__ __launch_bounds__(512) void scan2_kernel(const unsigned* __restrict__ bsum,
                                                    unsigned* __restrict__ bsum_ex, int nb) {
    __shared__ unsigned s[512];
    const int t = threadIdx.x;
    const unsigned v = (t < nb) ? bsum[t] : 0u;
    s[t] = v; __syncthreads();
    for (int off = 1; off < 512; off <<= 1) {
        const unsigned u = (t >= off) ? s[t - off] : 0u;
        __syncthreads();
        s[t] += u;
        __syncthreads();
    }
    if (t < nb) bsum_ex[t] = s[t] - v;
}

__global__ __launch_bounds__(256) void scan3_kernel(unsigned* __restrict__ row_start,
                                                    unsigned* __restrict__ cursor_aka_cnt,
                                                    float4* __restrict__ abl,
                                                    const unsigned* __restrict__ bsum_ex,
                                                    int N, int E) {
    const int i = blockIdx.x * 256 + threadIdx.x;
    if (i >= N) return;
    const unsigned incl = row_start[i];
    const unsigned c = cursor_aka_cnt[i];
    const unsigned start = bsum_ex[blockIdx.x] + incl - c;
    row_start[i] = start;
    cursor_aka_cnt[i] = start;
    abl[i].z = __logf((float)(c + 1u));   // .z only (.x,.y owned by gemm)
    if (i == N - 1) row_start[N] = (unsigned)E;
}

// ========== scatter positions only: sorted_col in CSR order (4 B/edge) ==========
__global__ __launch_bounds__(256) void scatter_pos_kernel(const int* __restrict__ row,
                                                          const int* __restrict__ col,
                                                          unsigned* __restrict__ cursor,
                                                          int* __restrict__ scol, int E) {
    const int i0 = (blockIdx.x * blockDim.x + threadIdx.x) * 4;
    if (i0 + 3 < E) {
        const int4 r4 = *(const int4*)&row[i0];
        const int4 c4 = *(const int4*)&col[i0];
        // 4 independent atomic chains -> latency overlap
        const unsigned p0 = atomicAdd(&cursor[r4.x], 1u);
        const unsigned p1 = atomicAdd(&cursor[r4.y], 1u);
        const unsigned p2 = atomicAdd(&cursor[r4.z], 1u);
        const unsigned p3 = atomicAdd(&cursor[r4.w], 1u);
        scol[p0] = c4.x;
        scol[p1] = c4.y;
        scol[p2] = c4.z;
        scol[p3] = c4.w;
    } else {
        for (int e = i0; e < E; e++) {
            const unsigned p = atomicAdd(&cursor[row[e]], 1u);
            scol[p] = col[e];
        }
    }
}

// ========== accumulate: wave per node, fused edge weight, relu fused ==========
__global__ __launch_bounds__(256) void accum_kernel(const unsigned short* __restrict__ pre16,
                                                    const int* __restrict__ scol,
                                                    const unsigned* __restrict__ row_start,
                                                    const float4* __restrict__ abl,
                                                    const float* __restrict__ f_b,
                                                    float* __restrict__ out, int N) {
    const int lane = threadIdx.x & 63;
    const int n = (int)((blockIdx.x * blockDim.x + threadIdx.x) >> 6);
    if (n >= N) return;
    const unsigned s0 = row_start[n], s1 = row_start[n + 1];
    const float4 me = abl[n];
    const float an = me.x + f_b[0];
    const float ldr = me.z;
    float acc = 0.f;
    unsigned j = s0;
    for (; j + 4 <= s1; j += 4) {
        const int c0 = scol[j], c1 = scol[j + 1], c2 = scol[j + 2], c3 = scol[j + 3];
        const float4 o0 = abl[c0], o1 = abl[c1], o2 = abl[c2], o3 = abl[c3];
        const float v0 = bf16_to_f32(pre16[(size_t)c0 * 64 + lane]);
        const float v1 = bf16_to_f32(pre16[(size_t)c1 * 64 + lane]);
        const float v2 = bf16_to_f32(pre16[(size_t)c2 * 64 + lane]);
        const float v3 = bf16_to_f32(pre16[(size_t)c3 * 64 + lane]);
        acc += __expf(-(an + o0.y) * (ldr + o0.z)) * v0;
        acc += __expf(-(an + o1.y) * (ldr + o1.z)) * v1;
        acc += __expf(-(an + o2.y) * (ldr + o2.z)) * v2;
        acc += __expf(-(an + o3.y) * (ldr + o3.z)) * v3;
    }
    for (; j < s1; j++) {
        const int c = scol[j];
        const float4 oc = abl[c];
        acc += __expf(-(an + oc.y) * (ldr + oc.z))
             * bf16_to_f32(pre16[(size_t)c * 64 + lane]);
    }
    out[(size_t)n * 64 + lane] = fmaxf(acc, 0.f);
}

// ========== fallback: atomic scatter (small ws) ==========
__global__ __launch_bounds__(256) void edge_atomic_kernel(const unsigned short* __restrict__ pre16,
                                                          const unsigned* __restrict__ cnt,
                                                          const float4* __restrict__ abl,
                                                          const float* __restrict__ f_b,
                                                          const int* __restrict__ row,
                                                          const int* __restrict__ col,
                                                          float* __restrict__ out, int E) {
    const int lane = threadIdx.x & 63;
    const int wave = (int)((blockIdx.x * blockDim.x + threadIdx.x) >> 6);
    const int nwaves = (int)((gridDim.x * blockDim.x) >> 6);
    const float fb = f_b[0];
    for (int e = wave; e < E; e += nwaves) {
        const int r = row[e];
        const int c = col[e];
        const float s = abl[r].x + abl[c].y + fb;
        const float d = (float)(cnt[r] + 1u) * (float)(cnt[c] + 1u);
        const float val = __expf(-s * __logf(d));
        atomicAdd(&out[(size_t)r * 64 + lane],
                  val * bf16_to_f32(pre16[(size_t)c * 64 + lane]));
    }
}

__global__ __launch_bounds__(256) void relu_kernel(float4* __restrict__ out, int n4) {
    const int i = blockIdx.x * blockDim.x + threadIdx.x;
    if (i < n4) {
        float4 v = out[i];
        v.x = fmaxf(v.x, 0.f); v.y = fmaxf(v.y, 0.f);
        v.z = fmaxf(v.z, 0.f); v.w = fmaxf(v.w, 0.f);
        out[i] = v;
    }
}

extern "C" void kernel_launch(void* const* d_in, const int* in_sizes, int n_in,
                              void* d_out, int out_size, void* d_ws, size_t ws_size,
                              hipStream_t stream) {
    const float* x   = (const float*)d_in[0];
    const float* W   = (const float*)d_in[1];
    const float* f_w = (const float*)d_in[2];
    const float* f_b = (const float*)d_in[3];
    const int*   row = (const int*)d_in[4];
    const int*   col = (const int*)d_in[5];
    float* out = (float*)d_out;

    const int N = in_sizes[0] / IN_DIM;   // 100000
    const int E = in_sizes[4];            // 1600000

    size_t off = 0;
    auto salloc = [&](size_t bytes) { size_t p = off; off = (off + bytes + 255) & ~(size_t)255; return p; };
    char* w8 = (char*)d_ws;
    unsigned short* pre16 = (unsigned short*)(w8 + salloc((size_t)N * OUT_DIM * sizeof(unsigned short)));
    unsigned* row_start = (unsigned*)(w8 + salloc((size_t)(N + 1) * sizeof(unsigned)));
    unsigned* cnt       = (unsigned*)(w8 + salloc((size_t)N * sizeof(unsigned)));   // later: cursor
    float4*   abl       = (float4*)  (w8 + salloc((size_t)N * sizeof(float4)));
    unsigned* bsum      = (unsigned*)(w8 + salloc(512 * sizeof(unsigned)));
    unsigned* bsum_ex   = (unsigned*)(w8 + salloc(512 * sizeof(unsigned)));
    short8*   wfrag     = (short8*)  (w8 + salloc(2048 * sizeof(short8)));
    float*    wf0       = (float*)   (w8 + salloc(256 * sizeof(float)));
    float*    wf1       = (float*)   (w8 + salloc(256 * sizeof(float)));
    int*      scol      = (int*)     (w8 + salloc((size_t)E * sizeof(int)));
    const size_t need_full = off;

    const int nb = (N + 255) / 256;
    const int nblk_gemm = (N + 63) / 64;
    const int nblk_node = (N + 3) / 4;
    const int nblk_edge = (E + 255) / 256;
    const int nblk_scat = ((E + 3) / 4 + 255) / 256;

    hipMemsetAsync(cnt, 0, (size_t)N * sizeof(unsigned), stream);
    wprep_kernel<<<1, 256, 0, stream>>>(W, f_w, wfrag, wf0, wf1);
    degree_kernel<<<nblk_edge, 256, 0, stream>>>(row, cnt, E);

    if (need_full <= ws_size) {
        scan1_kernel<<<nb, 256, 0, stream>>>(cnt, row_start, bsum, N);
        scan2_kernel<<<1, 512, 0, stream>>>(bsum, bsum_ex, nb);
        scan3_kernel<<<nb, 256, 0, stream>>>(row_start, cnt, abl, bsum_ex, N, E);
        gemm_kernel<<<nblk_gemm, 256, 0, stream>>>(x, wfrag, wf0, wf1, pre16, abl, N);
        scatter_pos_kernel<<<nblk_scat, 256, 0, stream>>>(row, col, cnt, scol, E);
        accum_kernel<<<nblk_node, 256, 0, stream>>>(pre16, scol, row_start, abl, f_b, out, N);
    } else {
        gemm_kernel<<<nblk_gemm, 256, 0, stream>>>(x, wfrag, wf0, wf1, pre16, abl, N);
        hipMemsetAsync(out, 0, (size_t)out_size * sizeof(float), stream);
        edge_atomic_kernel<<<4096, 256, 0, stream>>>(pre16, cnt, abl, f_b, row, col, out, E);
        const int n4 = out_size / 4;
        relu_kernel<<<(n4 + 255) / 256, 256, 0, stream>>>((float4*)out, n4);
    }
}

// Round 6
// 383.271 us; speedup vs baseline: 1.2362x; 1.2362x over previous
//
#include <hip/hip_runtime.h>

#define IN_DIM 256
#define OUT_DIM 64

typedef __attribute__((ext_vector_type(8))) short short8;   // 8 bf16 (4 VGPR)
typedef __attribute__((ext_vector_type(4))) float frag_cd;  // 4 fp32 acc

__device__ __forceinline__ unsigned short bf16_rne(float f) {
    unsigned u = __float_as_uint(f);
    u = (u + 0x7FFFu + ((u >> 16) & 1u)) >> 16;
    return (unsigned short)u;
}
__device__ __forceinline__ float bf16_to_f32(unsigned short h) {
    return __uint_as_float((unsigned)h << 16);
}

// ===== wprep: pack W into per-lane MFMA B-fragments (bf16) + wf0/wf1 = W @ f_w =====
__global__ __launch_bounds__(256) void wprep_kernel(const float* __restrict__ W,
                                                    const float* __restrict__ f_w,
                                                    short8* __restrict__ wfrag,
                                                    float* __restrict__ wf0,
                                                    float* __restrict__ wf1) {
    const int t = threadIdx.x;
    float s0 = 0.f, s1 = 0.f;
    #pragma unroll 8
    for (int c = 0; c < 64; c++) {
        const float w = W[t * 64 + c];
        s0 += w * f_w[c];
        s1 += w * f_w[64 + c];
    }
    wf0[t] = s0;
    wf1[t] = s1;
    for (int e = t; e < 2048; e += 256) {
        const int lane = e & 63;
        const int ct = e >> 6;
        const int chunk = ct >> 2, tile = ct & 3;
        const int kb = chunk * 32 + ((lane >> 4) * 8);
        const int n = tile * 16 + (lane & 15);
        short8 f;
        #pragma unroll
        for (int j = 0; j < 8; j++)
            f[j] = (short)bf16_rne(W[(kb + j) * 64 + n]);
        wfrag[e] = f;
    }
}

// ===== GEMM: pre16 = bf16(x @ W) via MFMA; abl.x/.y = exact fp32 x@wf0, x@wf1 =====
__global__ __launch_bounds__(256) void gemm_kernel(const float* __restrict__ x,
                                                   const short8* __restrict__ wfrag,
                                                   const float* __restrict__ wf0,
                                                   const float* __restrict__ wf1,
                                                   unsigned short* __restrict__ pre16,
                                                   float4* __restrict__ abl, int N) {
    const int t = threadIdx.x;
    const int w = t >> 6;
    const int l = t & 63;
    const int m = l & 15;
    const int q = l >> 4;
    const int row0 = blockIdx.x * 64 + w * 16;
    const int arow = row0 + m;
    const int arowc = (arow < N) ? arow : (N - 1);
    const float* xr = x + (size_t)arowc * IN_DIM;

    frag_cd acc0 = {0.f, 0.f, 0.f, 0.f};
    frag_cd acc1 = acc0, acc2 = acc0, acc3 = acc0;
    float ap = 0.f, bp = 0.f;

    #pragma unroll 2
    for (int c = 0; c < 8; c++) {
        const int k0 = c * 32 + q * 8;
        const float4 xl = *(const float4*)&xr[k0];
        const float4 xh = *(const float4*)&xr[k0 + 4];
        const float4 w0l = *(const float4*)&wf0[k0];
        const float4 w0h = *(const float4*)&wf0[k0 + 4];
        const float4 w1l = *(const float4*)&wf1[k0];
        const float4 w1h = *(const float4*)&wf1[k0 + 4];
        const short8 b0 = wfrag[(c * 4 + 0) * 64 + l];
        const short8 b1 = wfrag[(c * 4 + 1) * 64 + l];
        const short8 b2 = wfrag[(c * 4 + 2) * 64 + l];
        const short8 b3 = wfrag[(c * 4 + 3) * 64 + l];

        ap += xl.x * w0l.x + xl.y * w0l.y + xl.z * w0l.z + xl.w * w0l.w
            + xh.x * w0h.x + xh.y * w0h.y + xh.z * w0h.z + xh.w * w0h.w;
        bp += xl.x * w1l.x + xl.y * w1l.y + xl.z * w1l.z + xl.w * w1l.w
            + xh.x * w1h.x + xh.y * w1h.y + xh.z * w1h.z + xh.w * w1h.w;

        short8 a8;
        a8[0] = (short)bf16_rne(xl.x); a8[1] = (short)bf16_rne(xl.y);
        a8[2] = (short)bf16_rne(xl.z); a8[3] = (short)bf16_rne(xl.w);
        a8[4] = (short)bf16_rne(xh.x); a8[5] = (short)bf16_rne(xh.y);
        a8[6] = (short)bf16_rne(xh.z); a8[7] = (short)bf16_rne(xh.w);

        acc0 = __builtin_amdgcn_mfma_f32_16x16x32_bf16(a8, b0, acc0, 0, 0, 0);
        acc1 = __builtin_amdgcn_mfma_f32_16x16x32_bf16(a8, b1, acc1, 0, 0, 0);
        acc2 = __builtin_amdgcn_mfma_f32_16x16x32_bf16(a8, b2, acc2, 0, 0, 0);
        acc3 = __builtin_amdgcn_mfma_f32_16x16x32_bf16(a8, b3, acc3, 0, 0, 0);
    }

    ap += __shfl_xor(ap, 16, 64); ap += __shfl_xor(ap, 32, 64);
    bp += __shfl_xor(bp, 16, 64); bp += __shfl_xor(bp, 32, 64);
    if (q == 0 && arow < N)
        *(float2*)&abl[arow] = make_float2(ap, bp);   // .x,.y only (.z owned by scan3)

    const frag_cd* accs[4] = {&acc0, &acc1, &acc2, &acc3};
    #pragma unroll
    for (int tt = 0; tt < 4; tt++) {
        #pragma unroll
        for (int r = 0; r < 4; r++) {
            const int ro = row0 + q * 4 + r;
            if (ro < N)
                pre16[(size_t)ro * OUT_DIM + tt * 16 + m] = bf16_rne((*accs[tt])[r]);
        }
    }
}

// ===== rank: fused degree histogram + per-edge rank (coalesced rank write) =====
__global__ __launch_bounds__(256) void rank_kernel(const int* __restrict__ row,
                                                   unsigned* __restrict__ cnt,
                                                   unsigned* __restrict__ rank, int E) {
    const int i = blockIdx.x * blockDim.x + threadIdx.x;
    if (i < E) rank[i] = atomicAdd(&cnt[row[i]], 1u);
}

// ================= scan (3-phase) =================
__global__ __launch_bounds__(256) void scan1_kernel(const unsigned* __restrict__ cnt,
                                                    unsigned* __restrict__ incl,
                                                    unsigned* __restrict__ bsum, int N) {
    __shared__ unsigned s[256];
    const int t = threadIdx.x;
    const int i = blockIdx.x * 256 + t;
    const unsigned v = (i < N) ? cnt[i] : 0u;
    s[t] = v; __syncthreads();
    for (int off = 1; off < 256; off <<= 1) {
        const unsigned u = (t >= off) ? s[t - off] : 0u;
        __syncthreads();
        s[t] += u;
        __syncthreads();
    }
    if (i < N) incl[i] = s[t];
    if (t == 255) bsum[blockIdx.x] = s[255];
}

__global__ __launch_bounds__(512) void scan2_kernel(const unsigned* __restrict__ bsum,
                                                    unsigned* __restrict__ bsum_ex, int nb) {
    __shared__ unsigned s[512];
    const int t = threadIdx.x;
    const unsigned v = (t < nb) ? bsum[t] : 0u;
    s[t] = v; __syncthreads();
    for (int off = 1; off < 512; off <<= 1) {
        const unsigned u = (t >= off) ? s[t - off] : 0u;
        __syncthreads();
        s[t] += u;
        __syncthreads();
    }
    if (t < nb) bsum_ex[t] = s[t] - v;
}

// in-place: incl -> exclusive row_start; cnt stays = counts
__global__ __launch_bounds__(256) void scan3_kernel(unsigned* __restrict__ row_start,
                                                    const unsigned* __restrict__ cnt,
                                                    float4* __restrict__ abl,
                                                    const unsigned* __restrict__ bsum_ex,
                                                    int N, int E) {
    const int i = blockIdx.x * 256 + threadIdx.x;
    if (i >= N) return;
    const unsigned incl = row_start[i];
    const unsigned c = cnt[i];
    row_start[i] = bsum_ex[blockIdx.x] + incl - c;
    abl[i].z = __logf((float)(c + 1u));   // .z only (.x,.y owned by gemm)
    if (i == N - 1) row_start[N] = (unsigned)E;
}

// ===== scatter, atomic-free: scol[row_start[row[e]] + rank[e]] = col[e] =====
__global__ __launch_bounds__(256) void scatter_pos_kernel(const int* __restrict__ row,
                                                          const int* __restrict__ col,
                                                          const unsigned* __restrict__ rank,
                                                          const unsigned* __restrict__ row_start,
                                                          int* __restrict__ scol, int E) {
    const int e = blockIdx.x * blockDim.x + threadIdx.x;
    if (e < E)
        scol[row_start[row[e]] + rank[e]] = col[e];   // fire-and-forget store
}

// ========== accumulate: wave per node, fused edge weight, relu fused ==========
__global__ __launch_bounds__(256) void accum_kernel(const unsigned short* __restrict__ pre16,
                                                    const int* __restrict__ scol,
                                                    const unsigned* __restrict__ row_start,
                                                    const float4* __restrict__ abl,
                                                    const float* __restrict__ f_b,
                                                    float* __restrict__ out, int N) {
    const int lane = threadIdx.x & 63;
    const int n = (int)((blockIdx.x * blockDim.x + threadIdx.x) >> 6);
    if (n >= N) return;
    const unsigned s0 = row_start[n], s1 = row_start[n + 1];
    const float4 me = abl[n];
    const float an = me.x + f_b[0];
    const float ldr = me.z;
    float acc = 0.f;
    unsigned j = s0;
    for (; j + 4 <= s1; j += 4) {
        const int c0 = scol[j], c1 = scol[j + 1], c2 = scol[j + 2], c3 = scol[j + 3];
        const float4 o0 = abl[c0], o1 = abl[c1], o2 = abl[c2], o3 = abl[c3];
        const float v0 = bf16_to_f32(pre16[(size_t)c0 * 64 + lane]);
        const float v1 = bf16_to_f32(pre16[(size_t)c1 * 64 + lane]);
        const float v2 = bf16_to_f32(pre16[(size_t)c2 * 64 + lane]);
        const float v3 = bf16_to_f32(pre16[(size_t)c3 * 64 + lane]);
        acc += __expf(-(an + o0.y) * (ldr + o0.z)) * v0;
        acc += __expf(-(an + o1.y) * (ldr + o1.z)) * v1;
        acc += __expf(-(an + o2.y) * (ldr + o2.z)) * v2;
        acc += __expf(-(an + o3.y) * (ldr + o3.z)) * v3;
    }
    for (; j < s1; j++) {
        const int c = scol[j];
        const float4 oc = abl[c];
        acc += __expf(-(an + oc.y) * (ldr + oc.z))
             * bf16_to_f32(pre16[(size_t)c * 64 + lane]);
    }
    out[(size_t)n * 64 + lane] = fmaxf(acc, 0.f);
}

// ========== fallback: atomic scatter (small ws) ==========
__global__ __launch_bounds__(256) void edge_atomic_kernel(const unsigned short* __restrict__ pre16,
                                                          const unsigned* __restrict__ cnt,
                                                          const float4* __restrict__ abl,
                                                          const float* __restrict__ f_b,
                                                          const int* __restrict__ row,
                                                          const int* __restrict__ col,
                                                          float* __restrict__ out, int E) {
    const int lane = threadIdx.x & 63;
    const int wave = (int)((blockIdx.x * blockDim.x + threadIdx.x) >> 6);
    const int nwaves = (int)((gridDim.x * blockDim.x) >> 6);
    const float fb = f_b[0];
    for (int e = wave; e < E; e += nwaves) {
        const int r = row[e];
        const int c = col[e];
        const float s = abl[r].x + abl[c].y + fb;
        const float d = (float)(cnt[r] + 1u) * (float)(cnt[c] + 1u);
        const float val = __expf(-s * __logf(d));
        atomicAdd(&out[(size_t)r * 64 + lane],
                  val * bf16_to_f32(pre16[(size_t)c * 64 + lane]));
    }
}

__global__ __launch_bounds__(256) void relu_kernel(float4* __restrict__ out, int n4) {
    const int i = blockIdx.x * blockDim.x + threadIdx.x;
    if (i < n4) {
        float4 v = out[i];
        v.x = fmaxf(v.x, 0.f); v.y = fmaxf(v.y, 0.f);
        v.z = fmaxf(v.z, 0.f); v.w = fmaxf(v.w, 0.f);
        out[i] = v;
    }
}

extern "C" void kernel_launch(void* const* d_in, const int* in_sizes, int n_in,
                              void* d_out, int out_size, void* d_ws, size_t ws_size,
                              hipStream_t stream) {
    const float* x   = (const float*)d_in[0];
    const float* W   = (const float*)d_in[1];
    const float* f_w = (const float*)d_in[2];
    const float* f_b = (const float*)d_in[3];
    const int*   row = (const int*)d_in[4];
    const int*   col = (const int*)d_in[5];
    float* out = (float*)d_out;

    const int N = in_sizes[0] / IN_DIM;   // 100000
    const int E = in_sizes[4];            // 1600000

    size_t off = 0;
    auto salloc = [&](size_t bytes) { size_t p = off; off = (off + bytes + 255) & ~(size_t)255; return p; };
    char* w8 = (char*)d_ws;
    unsigned short* pre16 = (unsigned short*)(w8 + salloc((size_t)N * OUT_DIM * sizeof(unsigned short)));
    unsigned* row_start = (unsigned*)(w8 + salloc((size_t)(N + 1) * sizeof(unsigned)));
    unsigned* cnt       = (unsigned*)(w8 + salloc((size_t)N * sizeof(unsigned)));
    float4*   abl       = (float4*)  (w8 + salloc((size_t)N * sizeof(float4)));
    unsigned* bsum      = (unsigned*)(w8 + salloc(512 * sizeof(unsigned)));
    unsigned* bsum_ex   = (unsigned*)(w8 + salloc(512 * sizeof(unsigned)));
    short8*   wfrag     = (short8*)  (w8 + salloc(2048 * sizeof(short8)));
    float*    wf0       = (float*)   (w8 + salloc(256 * sizeof(float)));
    float*    wf1       = (float*)   (w8 + salloc(256 * sizeof(float)));
    int*      scol      = (int*)     (w8 + salloc((size_t)E * sizeof(int)));
    unsigned* rank      = (unsigned*)(w8 + salloc((size_t)E * sizeof(unsigned)));
    const size_t need_full = off;

    const int nb = (N + 255) / 256;
    const int nblk_gemm = (N + 63) / 64;
    const int nblk_node = (N + 3) / 4;
    const int nblk_edge = (E + 255) / 256;

    hipMemsetAsync(cnt, 0, (size_t)N * sizeof(unsigned), stream);
    wprep_kernel<<<1, 256, 0, stream>>>(W, f_w, wfrag, wf0, wf1);

    if (need_full <= ws_size) {
        rank_kernel<<<nblk_edge, 256, 0, stream>>>(row, cnt, rank, E);
        scan1_kernel<<<nb, 256, 0, stream>>>(cnt, row_start, bsum, N);
        scan2_kernel<<<1, 512, 0, stream>>>(bsum, bsum_ex, nb);
        scan3_kernel<<<nb, 256, 0, stream>>>(row_start, cnt, abl, bsum_ex, N, E);
        gemm_kernel<<<nblk_gemm, 256, 0, stream>>>(x, wfrag, wf0, wf1, pre16, abl, N);
        scatter_pos_kernel<<<nblk_edge, 256, 0, stream>>>(row, col, rank, row_start, scol, E);
        accum_kernel<<<nblk_node, 256, 0, stream>>>(pre16, scol, row_start, abl, f_b, out, N);
    } else {
        unsigned* cnt2 = cnt;  // fallback only needs counts
        rank_kernel<<<nblk_edge, 256, 0, stream>>>(row, cnt2, (unsigned*)scol, E);
        scan1_kernel<<<nb, 256, 0, stream>>>(cnt2, row_start, bsum, N);  // degf via abl.z below
        scan2_kernel<<<1, 512, 0, stream>>>(bsum, bsum_ex, nb);
        scan3_kernel<<<nb, 256, 0, stream>>>(row_start, cnt2, abl, bsum_ex, N, E);
        gemm_kernel<<<nblk_gemm, 256, 0, stream>>>(x, wfrag, wf0, wf1, pre16, abl, N);
        hipMemsetAsync(out, 0, (size_t)out_size * sizeof(float), stream);
        edge_atomic_kernel<<<4096, 256, 0, stream>>>(pre16, cnt2, abl, f_b, row, col, out, E);
        const int n4 = out_size / 4;
        relu_kernel<<<(n4 + 255) / 256, 256, 0, stream>>>((float4*)out, n4);
    }
}

// Round 7
// 329.218 us; speedup vs baseline: 1.4392x; 1.1642x over previous
//
#include <hip/hip_runtime.h>

#define IN_DIM 256
#define OUT_DIM 64

typedef __attribute__((ext_vector_type(8))) short short8;   // 8 bf16 (4 VGPR)
typedef __attribute__((ext_vector_type(4))) float frag_cd;  // 4 fp32 acc

__device__ __forceinline__ unsigned short bf16_rne(float f) {
    unsigned u = __float_as_uint(f);
    u = (u + 0x7FFFu + ((u >> 16) & 1u)) >> 16;
    return (unsigned short)u;
}
__device__ __forceinline__ float bf16_to_f32(unsigned short h) {
    return __uint_as_float((unsigned)h << 16);
}

// ===== wprep: pack W into per-lane MFMA B-fragments (bf16) + wf0/wf1 = W @ f_w =====
__global__ __launch_bounds__(256) void wprep_kernel(const float* __restrict__ W,
                                                    const float* __restrict__ f_w,
                                                    short8* __restrict__ wfrag,
                                                    float* __restrict__ wf0,
                                                    float* __restrict__ wf1) {
    const int t = threadIdx.x;
    float s0 = 0.f, s1 = 0.f;
    #pragma unroll 8
    for (int c = 0; c < 64; c++) {
        const float w = W[t * 64 + c];
        s0 += w * f_w[c];
        s1 += w * f_w[64 + c];
    }
    wf0[t] = s0;
    wf1[t] = s1;
    for (int e = t; e < 2048; e += 256) {
        const int lane = e & 63;
        const int ct = e >> 6;
        const int chunk = ct >> 2, tile = ct & 3;
        const int kb = chunk * 32 + ((lane >> 4) * 8);
        const int n = tile * 16 + (lane & 15);
        short8 f;
        #pragma unroll
        for (int j = 0; j < 8; j++)
            f[j] = (short)bf16_rne(W[(kb + j) * 64 + n]);
        wfrag[e] = f;
    }
}

// ===== fused: gemm (MFMA) blocks interleaved with rank (atomic histogram) blocks =====
// stripe of 5: blockIdx%5==4 -> gemm block (blockIdx/5); else rank block.
// gemm: pre16 = bf16(x@W); a[r] = x·wf0 (fp32); bl[r].x = x·wf1 (fp32).
// rank: rank[e] = atomicAdd(cnt[row[e]],1)  — latency hidden by co-resident gemm blocks.
__global__ __launch_bounds__(256) void gemm_rank_kernel(const float* __restrict__ x,
                                                        const short8* __restrict__ wfrag,
                                                        const float* __restrict__ wf0,
                                                        const float* __restrict__ wf1,
                                                        unsigned short* __restrict__ pre16,
                                                        float* __restrict__ a,
                                                        float2* __restrict__ bl,
                                                        const int* __restrict__ row,
                                                        unsigned* __restrict__ cnt,
                                                        unsigned* __restrict__ rank,
                                                        int N, int E,
                                                        int nblk_gemm, int nblk_rank) {
    const int s = blockIdx.x / 5;
    const int r5 = blockIdx.x % 5;
    if (r5 != 4) {
        // ---- rank path ----
        const int rb = s * 4 + r5;
        if (rb >= nblk_rank) return;
        const int i = rb * 256 + threadIdx.x;
        if (i < E) {
            const unsigned rk = atomicAdd(&cnt[row[i]], 1u);
            if (rank) rank[i] = rk;
        }
        return;
    }
    // ---- gemm path ----
    if (s >= nblk_gemm) return;
    const int t = threadIdx.x;
    const int w = t >> 6;
    const int l = t & 63;
    const int m = l & 15;
    const int q = l >> 4;
    const int row0 = s * 64 + w * 16;
    const int arow = row0 + m;
    const int arowc = (arow < N) ? arow : (N - 1);
    const float* xr = x + (size_t)arowc * IN_DIM;

    frag_cd acc0 = {0.f, 0.f, 0.f, 0.f};
    frag_cd acc1 = acc0, acc2 = acc0, acc3 = acc0;
    float ap = 0.f, bp = 0.f;

    #pragma unroll 2
    for (int c = 0; c < 8; c++) {
        const int k0 = c * 32 + q * 8;
        const float4 xl = *(const float4*)&xr[k0];
        const float4 xh = *(const float4*)&xr[k0 + 4];
        const float4 w0l = *(const float4*)&wf0[k0];
        const float4 w0h = *(const float4*)&wf0[k0 + 4];
        const float4 w1l = *(const float4*)&wf1[k0];
        const float4 w1h = *(const float4*)&wf1[k0 + 4];
        const short8 b0 = wfrag[(c * 4 + 0) * 64 + l];
        const short8 b1 = wfrag[(c * 4 + 1) * 64 + l];
        const short8 b2 = wfrag[(c * 4 + 2) * 64 + l];
        const short8 b3 = wfrag[(c * 4 + 3) * 64 + l];

        ap += xl.x * w0l.x + xl.y * w0l.y + xl.z * w0l.z + xl.w * w0l.w
            + xh.x * w0h.x + xh.y * w0h.y + xh.z * w0h.z + xh.w * w0h.w;
        bp += xl.x * w1l.x + xl.y * w1l.y + xl.z * w1l.z + xl.w * w1l.w
            + xh.x * w1h.x + xh.y * w1h.y + xh.z * w1h.z + xh.w * w1h.w;

        short8 a8;
        a8[0] = (short)bf16_rne(xl.x); a8[1] = (short)bf16_rne(xl.y);
        a8[2] = (short)bf16_rne(xl.z); a8[3] = (short)bf16_rne(xl.w);
        a8[4] = (short)bf16_rne(xh.x); a8[5] = (short)bf16_rne(xh.y);
        a8[6] = (short)bf16_rne(xh.z); a8[7] = (short)bf16_rne(xh.w);

        acc0 = __builtin_amdgcn_mfma_f32_16x16x32_bf16(a8, b0, acc0, 0, 0, 0);
        acc1 = __builtin_amdgcn_mfma_f32_16x16x32_bf16(a8, b1, acc1, 0, 0, 0);
        acc2 = __builtin_amdgcn_mfma_f32_16x16x32_bf16(a8, b2, acc2, 0, 0, 0);
        acc3 = __builtin_amdgcn_mfma_f32_16x16x32_bf16(a8, b3, acc3, 0, 0, 0);
    }

    ap += __shfl_xor(ap, 16, 64); ap += __shfl_xor(ap, 32, 64);
    bp += __shfl_xor(bp, 16, 64); bp += __shfl_xor(bp, 32, 64);
    if (q == 0 && arow < N) { a[arow] = ap; bl[arow].x = bp; }  // .y owned by scan3

    const frag_cd* accs[4] = {&acc0, &acc1, &acc2, &acc3};
    #pragma unroll
    for (int tt = 0; tt < 4; tt++) {
        #pragma unroll
        for (int r = 0; r < 4; r++) {
            const int ro = row0 + q * 4 + r;
            if (ro < N)
                pre16[(size_t)ro * OUT_DIM + tt * 16 + m] = bf16_rne((*accs[tt])[r]);
        }
    }
}

// ================= scan (3-phase) =================
__global__ __launch_bounds__(256) void scan1_kernel(const unsigned* __restrict__ cnt,
                                                    unsigned* __restrict__ incl,
                                                    unsigned* __restrict__ bsum, int N) {
    __shared__ unsigned s[256];
    const int t = threadIdx.x;
    const int i = blockIdx.x * 256 + t;
    const unsigned v = (i < N) ? cnt[i] : 0u;
    s[t] = v; __syncthreads();
    for (int off = 1; off < 256; off <<= 1) {
        const unsigned u = (t >= off) ? s[t - off] : 0u;
        __syncthreads();
        s[t] += u;
        __syncthreads();
    }
    if (i < N) incl[i] = s[t];
    if (t == 255) bsum[blockIdx.x] = s[255];
}

__global__ __launch_bounds__(512) void scan2_kernel(const unsigned* __restrict__ bsum,
                                                    unsigned* __restrict__ bsum_ex, int nb) {
    __shared__ unsigned s[512];
    const int t = threadIdx.x;
    const unsigned v = (t < nb) ? bsum[t] : 0u;
    s[t] = v; __syncthreads();
    for (int off = 1; off < 512; off <<= 1) {
        const unsigned u = (t >= off) ? s[t - off] : 0u;
        __syncthreads();
        s[t] += u;
        __syncthreads();
    }
    if (t < nb) bsum_ex[t] = s[t] - v;
}

// in-place: incl -> exclusive row_start; bl[i].y = log(deg)
__global__ __launch_bounds__(256) void scan3_kernel(unsigned* __restrict__ row_start,
                                                    const unsigned* __restrict__ cnt,
                                                    float2* __restrict__ bl,
                                                    const unsigned* __restrict__ bsum_ex,
                                                    int N, int E) {
    const int i = blockIdx.x * 256 + threadIdx.x;
    if (i >= N) return;
    const unsigned incl = row_start[i];
    const unsigned c = cnt[i];
    row_start[i] = bsum_ex[blockIdx.x] + incl - c;
    bl[i].y = __logf((float)(c + 1u));
    if (i == N - 1) row_start[N] = (unsigned)E;
}

// ===== scatter, atomic-free: scol[row_start[row[e]] + rank[e]] = col[e] =====
__global__ __launch_bounds__(256) void scatter_pos_kernel(const int* __restrict__ row,
                                                          const int* __restrict__ col,
                                                          const unsigned* __restrict__ rank,
                                                          const unsigned* __restrict__ row_start,
                                                          int* __restrict__ scol, int E) {
    const int e = blockIdx.x * blockDim.x + threadIdx.x;
    if (e < E)
        scol[row_start[row[e]] + rank[e]] = col[e];   // fire-and-forget store
}

// ========== accumulate v2: wave per node, 2 edges per instruction ==========
// lane = (eo = lane>>5, d = lane&31): half-wave eo handles edge j+eo, lane holds
// dim-pair (2d, 2d+1) as one uint (2×bf16). Combine halves via shfl_xor(32).
__global__ __launch_bounds__(256) void accum_kernel(const unsigned short* __restrict__ pre16,
                                                    const int* __restrict__ scol,
                                                    const unsigned* __restrict__ row_start,
                                                    const float* __restrict__ a,
                                                    const float2* __restrict__ bl,
                                                    const float* __restrict__ f_b,
                                                    float* __restrict__ out, int N) {
    const int lane = threadIdx.x & 63;
    const int eo = lane >> 5;
    const int d = lane & 31;
    const int n = (int)((blockIdx.x * blockDim.x + threadIdx.x) >> 6);
    if (n >= N) return;
    const unsigned* __restrict__ pre32 = (const unsigned*)pre16;
    const unsigned s0 = row_start[n], s1 = row_start[n + 1];
    const float an = a[n] + f_b[0];
    const float ldr = bl[n].y;
    float accx = 0.f, accy = 0.f;
    unsigned j = s0;
    for (; j + 4 <= s1; j += 4) {
        const int c0 = scol[j + eo];
        const int c1 = scol[j + 2 + eo];
        const float2 o0 = bl[c0];
        const float2 o1 = bl[c1];
        const unsigned p0 = pre32[(size_t)c0 * 32 + d];
        const unsigned p1 = pre32[(size_t)c1 * 32 + d];
        const float v0 = __expf(-(an + o0.x) * (ldr + o0.y));
        const float v1 = __expf(-(an + o1.x) * (ldr + o1.y));
        accx += v0 * bf16_to_f32((unsigned short)(p0 & 0xffffu));
        accy += v0 * bf16_to_f32((unsigned short)(p0 >> 16));
        accx += v1 * bf16_to_f32((unsigned short)(p1 & 0xffffu));
        accy += v1 * bf16_to_f32((unsigned short)(p1 >> 16));
    }
    if (j + 2 <= s1) {
        const int c0 = scol[j + eo];
        const float2 o0 = bl[c0];
        const unsigned p0 = pre32[(size_t)c0 * 32 + d];
        const float v0 = __expf(-(an + o0.x) * (ldr + o0.y));
        accx += v0 * bf16_to_f32((unsigned short)(p0 & 0xffffu));
        accy += v0 * bf16_to_f32((unsigned short)(p0 >> 16));
        j += 2;
    }
    if (j < s1 && eo == 0) {       // odd leftover edge: half 0 only
        const int c0 = scol[j];
        const float2 o0 = bl[c0];
        const unsigned p0 = pre32[(size_t)c0 * 32 + d];
        const float v0 = __expf(-(an + o0.x) * (ldr + o0.y));
        accx += v0 * bf16_to_f32((unsigned short)(p0 & 0xffffu));
        accy += v0 * bf16_to_f32((unsigned short)(p0 >> 16));
    }
    accx += __shfl_xor(accx, 32, 64);
    accy += __shfl_xor(accy, 32, 64);
    if (eo == 0) {
        const float2 o = make_float2(fmaxf(accx, 0.f), fmaxf(accy, 0.f));
        *(float2*)&out[(size_t)n * 64 + 2 * d] = o;
    }
}

// ========== fallback: atomic scatter (small ws) ==========
__global__ __launch_bounds__(256) void edge_atomic_kernel(const unsigned short* __restrict__ pre16,
                                                          const float* __restrict__ a,
                                                          const float2* __restrict__ bl,
                                                          const float* __restrict__ f_b,
                                                          const int* __restrict__ row,
                                                          const int* __restrict__ col,
                                                          float* __restrict__ out, int E) {
    const int lane = threadIdx.x & 63;
    const int wave = (int)((blockIdx.x * blockDim.x + threadIdx.x) >> 6);
    const int nwaves = (int)((gridDim.x * blockDim.x) >> 6);
    const float fb = f_b[0];
    for (int e = wave; e < E; e += nwaves) {
        const int r = row[e];
        const int c = col[e];
        const float s = a[r] + bl[c].x + fb;
        const float val = __expf(-s * (bl[r].y + bl[c].y));
        atomicAdd(&out[(size_t)r * 64 + lane],
                  val * bf16_to_f32(pre16[(size_t)c * 64 + lane]));
    }
}

__global__ __launch_bounds__(256) void relu_kernel(float4* __restrict__ out, int n4) {
    const int i = blockIdx.x * blockDim.x + threadIdx.x;
    if (i < n4) {
        float4 v = out[i];
        v.x = fmaxf(v.x, 0.f); v.y = fmaxf(v.y, 0.f);
        v.z = fmaxf(v.z, 0.f); v.w = fmaxf(v.w, 0.f);
        out[i] = v;
    }
}

extern "C" void kernel_launch(void* const* d_in, const int* in_sizes, int n_in,
                              void* d_out, int out_size, void* d_ws, size_t ws_size,
                              hipStream_t stream) {
    const float* x   = (const float*)d_in[0];
    const float* W   = (const float*)d_in[1];
    const float* f_w = (const float*)d_in[2];
    const float* f_b = (const float*)d_in[3];
    const int*   row = (const int*)d_in[4];
    const int*   col = (const int*)d_in[5];
    float* out = (float*)d_out;

    const int N = in_sizes[0] / IN_DIM;   // 100000
    const int E = in_sizes[4];            // 1600000

    size_t off = 0;
    auto salloc = [&](size_t bytes) { size_t p = off; off = (off + bytes + 255) & ~(size_t)255; return p; };
    char* w8 = (char*)d_ws;
    unsigned short* pre16 = (unsigned short*)(w8 + salloc((size_t)N * OUT_DIM * sizeof(unsigned short)));
    unsigned* row_start = (unsigned*)(w8 + salloc((size_t)(N + 1) * sizeof(unsigned)));
    unsigned* cnt       = (unsigned*)(w8 + salloc((size_t)N * sizeof(unsigned)));
    float*    a         = (float*)   (w8 + salloc((size_t)N * sizeof(float)));
    float2*   bl        = (float2*)  (w8 + salloc((size_t)N * sizeof(float2)));
    unsigned* bsum      = (unsigned*)(w8 + salloc(512 * sizeof(unsigned)));
    unsigned* bsum_ex   = (unsigned*)(w8 + salloc(512 * sizeof(unsigned)));
    short8*   wfrag     = (short8*)  (w8 + salloc(2048 * sizeof(short8)));
    float*    wf0       = (float*)   (w8 + salloc(256 * sizeof(float)));
    float*    wf1       = (float*)   (w8 + salloc(256 * sizeof(float)));
    int*      scol      = (int*)     (w8 + salloc((size_t)E * sizeof(int)));
    unsigned* rank      = (unsigned*)(w8 + salloc((size_t)E * sizeof(unsigned)));
    const size_t need_full = off;

    const int nb = (N + 255) / 256;
    const int nblk_gemm = (N + 63) / 64;
    const int nblk_node = (N + 3) / 4;
    const int nblk_edge = (E + 255) / 256;
    const int stripes = (((nblk_edge + 3) / 4) > nblk_gemm) ? ((nblk_edge + 3) / 4) : nblk_gemm;
    const int nblk_fused = stripes * 5;

    hipMemsetAsync(cnt, 0, (size_t)N * sizeof(unsigned), stream);
    wprep_kernel<<<1, 256, 0, stream>>>(W, f_w, wfrag, wf0, wf1);

    if (need_full <= ws_size) {
        gemm_rank_kernel<<<nblk_fused, 256, 0, stream>>>(x, wfrag, wf0, wf1, pre16, a, bl,
                                                         row, cnt, rank, N, E,
                                                         nblk_gemm, nblk_edge);
        scan1_kernel<<<nb, 256, 0, stream>>>(cnt, row_start, bsum, N);
        scan2_kernel<<<1, 512, 0, stream>>>(bsum, bsum_ex, nb);
        scan3_kernel<<<nb, 256, 0, stream>>>(row_start, cnt, bl, bsum_ex, N, E);
        scatter_pos_kernel<<<nblk_edge, 256, 0, stream>>>(row, col, rank, row_start, scol, E);
        accum_kernel<<<nblk_node, 256, 0, stream>>>(pre16, scol, row_start, a, bl, f_b, out, N);
    } else {
        gemm_rank_kernel<<<nblk_fused, 256, 0, stream>>>(x, wfrag, wf0, wf1, pre16, a, bl,
                                                         row, cnt, (unsigned*)nullptr, N, E,
                                                         nblk_gemm, nblk_edge);
        scan1_kernel<<<nb, 256, 0, stream>>>(cnt, row_start, bsum, N);
        scan2_kernel<<<1, 512, 0, stream>>>(bsum, bsum_ex, nb);
        scan3_kernel<<<nb, 256, 0, stream>>>(row_start, cnt, bl, bsum_ex, N, E);
        hipMemsetAsync(out, 0, (size_t)out_size * sizeof(float), stream);
        edge_atomic_kernel<<<4096, 256, 0, stream>>>(pre16, a, bl, f_b, row, col, out, E);
        const int n4 = out_size / 4;
        relu_kernel<<<(n4 + 255) / 256, 256, 0, stream>>>((float4*)out, n4);
    }
}